// Round 8
// baseline (2460.506 us; speedup 1.0000x reference)
//
#include <hip/hip_runtime.h>

#define F 128
#define RPB 64          // rows per bucket
#define MAXNB 1792      // LDS histogram capacity
#define CHUNK 8192      // edges per scatter/histo block
#define EPT 32          // edges per thread (CHUNK/256)

// ---------------- fallback: atomic COO (round-4 proven) ----------------
__global__ void spmm_coo_atomic(const int* __restrict__ rows,
                                const int* __restrict__ cols,
                                const float* __restrict__ vals,
                                const float* __restrict__ x,
                                float* __restrict__ out,
                                int nnz, int n_rows) {
    int t = blockIdx.x * blockDim.x + threadIdx.x;
    int e = t >> 5;
    int g = t & 31;
    if (e >= nnz) return;
    int r = rows[e];
    int c = cols[e];
    float v = vals[e];
    if ((unsigned)r >= (unsigned)n_rows || (unsigned)c >= (unsigned)n_rows) return;
    const float4 xv = *reinterpret_cast<const float4*>(x + (size_t)c * F + g * 4);
    float* o = out + (size_t)r * F + g * 4;
    atomicAdd(o + 0, v * xv.x);
    atomicAdd(o + 1, v * xv.y);
    atomicAdd(o + 2, v * xv.z);
    atomicAdd(o + 3, v * xv.w);
}

// ---------------- K1: block-aggregated bucket histogram ----------------
__global__ void k_bucket_histo(const int* __restrict__ rows, int* __restrict__ cnt,
                               int nnz, int nb, int n) {
    __shared__ int lc[MAXNB];
    for (int i = threadIdx.x; i < nb; i += 256) lc[i] = 0;
    __syncthreads();
    int base = blockIdx.x * CHUNK;
#pragma unroll
    for (int k = 0; k < EPT; ++k) {
        int e = base + k * 256 + threadIdx.x;
        if (e < nnz) {
            int r = rows[e];
            if ((unsigned)r < (unsigned)n) atomicAdd(&lc[r / RPB], 1);
        }
    }
    __syncthreads();
    for (int i = threadIdx.x; i < nb; i += 256) {
        int c = lc[i];
        if (c) atomicAdd(&cnt[i], c);
    }
}

// ---------------- K2: single-block exclusive scan over buckets ----------------
__global__ void k_bucket_scan(const int* __restrict__ cnt, int* __restrict__ off,
                              int* __restrict__ gcur, int nb) {
    __shared__ int s[256];
    int tid = threadIdx.x;
    int per = (nb + 255) / 256;      // <= 7 for nb <= 1792
    int base = tid * per;
    int loc[8];
    int tsum = 0;
#pragma unroll
    for (int k = 0; k < 8; ++k) {
        int i = base + k;
        int v = (k < per && i < nb) ? cnt[i] : 0;
        loc[k] = v;
        tsum += v;
    }
    s[tid] = tsum;
    __syncthreads();
    for (int o = 1; o < 256; o <<= 1) {
        int t = (tid >= o) ? s[tid - o] : 0;
        __syncthreads();
        s[tid] += t;
        __syncthreads();
    }
    int run = s[tid] - tsum;
#pragma unroll
    for (int k = 0; k < 8; ++k) {
        int i = base + k;
        if (k < per && i < nb) { off[i] = run; gcur[i] = run; }
        run += loc[k];
    }
    if (tid == 255) off[nb] = s[255];
}

// ---------------- K3: ranked bucket scatter (coalesced runs) ----------------
__global__ void k_rank_scatter(const int* __restrict__ rows, const int* __restrict__ cols,
                               const float* __restrict__ vals, int* __restrict__ gcur,
                               int2* __restrict__ pair, int nnz, int nb, int n) {
    __shared__ int lcnt[MAXNB];
    __shared__ int lbase[MAXNB];
    for (int i = threadIdx.x; i < nb; i += 256) lcnt[i] = 0;
    __syncthreads();
    int base = blockIdx.x * CHUNK;
    unsigned br[EPT];                 // packed (bucket << 13) | rank, rank < 8192
#pragma unroll
    for (int k = 0; k < EPT; ++k) {
        int e = base + k * 256 + threadIdx.x;
        br[k] = 0xFFFFFFFFu;
        if (e < nnz) {
            int r = rows[e];
            if ((unsigned)r < (unsigned)n) {
                int b = r / RPB;
                int rk = atomicAdd(&lcnt[b], 1);
                br[k] = ((unsigned)b << 13) | (unsigned)rk;
            }
        }
    }
    __syncthreads();
    for (int i = threadIdx.x; i < nb; i += 256) {
        int c = lcnt[i];
        if (c) lbase[i] = atomicAdd(&gcur[i], c);
    }
    __syncthreads();
#pragma unroll
    for (int k = 0; k < EPT; ++k) {
        if (br[k] != 0xFFFFFFFFu) {
            int e = base + k * 256 + threadIdx.x;
            int b = br[k] >> 13;
            int rk = br[k] & 0x1FFF;
            int lr = rows[e] - b * RPB;           // localrow in [0, RPB)
            int c = cols[e];
            if ((unsigned)c >= (unsigned)n) c = 0;  // defensive (vals impact unchanged for valid data)
            int pos = lbase[b] + rk;
            pair[pos] = make_int2((lr << 17) | c, __float_as_int(vals[e]));
        }
    }
}

// ---------------- K4: per-bucket SpMM with LDS tile ----------------
// 4 waves: wave = (edge parity, feature half). Each wave gathers 64 contiguous
// floats of x per edge and LDS-atomically accumulates into the 64x128 tile.
__global__ void __launch_bounds__(256) k_bucket_spmm(const int* __restrict__ off,
                                                     const int2* __restrict__ pair,
                                                     const float* __restrict__ x,
                                                     float* __restrict__ out, int n) {
    __shared__ float tile[RPB * F];
    int tid = threadIdx.x;
    int b = blockIdx.x;
#pragma unroll
    for (int i = 0; i < (RPB * F / 4) / 256; ++i)
        *reinterpret_cast<float4*>(&tile[(tid + i * 256) * 4]) = make_float4(0.f, 0.f, 0.f, 0.f);
    __syncthreads();

    int beg = off[b], end = off[b + 1];
    int wave = tid >> 6;
    int lane = tid & 63;
    int fh = wave & 1;       // feature half: [fh*64, fh*64+64)
    int eo = wave >> 1;      // edge parity
    const float* xb = x + fh * 64 + lane;
    float* tb = tile + fh * 64 + lane;

#pragma unroll 4
    for (int j = beg + eo; j < end; j += 2) {
        int2 pr = pair[j];
        int col = pr.x & 0x1FFFF;
        int lr = pr.x >> 17;
        float v = __int_as_float(pr.y);
        float xv = xb[(size_t)col * F];
        atomicAdd(&tb[lr * F], v * xv);
    }
    __syncthreads();

    size_t row0 = (size_t)b * RPB;
#pragma unroll
    for (int i = 0; i < (RPB * F / 4) / 256; ++i) {
        int i4 = tid + i * 256;          // float4 index, 32 per row
        int lr = i4 >> 5;
        long long rw = (long long)row0 + lr;
        if (rw < n)
            *reinterpret_cast<float4*>(&out[(size_t)rw * F + (i4 & 31) * 4]) =
                *reinterpret_cast<const float4*>(&tile[i4 * 4]);
    }
}

extern "C" void kernel_launch(void* const* d_in, const int* in_sizes, int n_in,
                              void* d_out, int out_size, void* d_ws, size_t ws_size,
                              hipStream_t stream) {
    const float* x = (const float*)d_in[0];
    const int* A_ind = (const int*)d_in[1];
    const float* A_val = (const float*)d_in[2];
    float* out = (float*)d_out;

    const int nnz = in_sizes[2];
    const int n = out_size / F;              // 100000
    const int nb = (n + RPB - 1) / RPB;      // 1563 buckets
    const int* rows = A_ind;
    const int* cols = A_ind + nnz;

    const size_t need = (size_t)nnz * 8 + (size_t)(3 * nb + 1) * 4 + 64;

    if (nb > MAXNB || ws_size < need) {
        hipMemsetAsync(d_out, 0, (size_t)out_size * sizeof(float), stream);
        const long long total = (long long)nnz * 32;
        spmm_coo_atomic<<<(int)((total + 255) / 256), 256, 0, stream>>>(
            rows, cols, A_val, x, out, nnz, n);
        return;
    }

    char* w = (char*)d_ws;
    int2* pair = (int2*)w;     w += (size_t)nnz * 8;
    int* cnt = (int*)w;        w += (size_t)nb * 4;
    int* off = (int*)w;        w += (size_t)(nb + 1) * 4;
    int* gcur = (int*)w;

    const int nchunks = (nnz + CHUNK - 1) / CHUNK;

    hipMemsetAsync(cnt, 0, (size_t)nb * 4, stream);
    k_bucket_histo<<<nchunks, 256, 0, stream>>>(rows, cnt, nnz, nb, n);
    k_bucket_scan<<<1, 256, 0, stream>>>(cnt, off, gcur, nb);
    k_rank_scatter<<<nchunks, 256, 0, stream>>>(rows, cols, A_val, gcur, pair, nnz, nb, n);
    // Writes every output row exactly once (zeros for empty rows) -> no out memset.
    k_bucket_spmm<<<nb, 256, 0, stream>>>(off, pair, x, out, n);
}

// Round 9
// 445.854 us; speedup vs baseline: 5.5186x; 5.5186x over previous
//
#include <hip/hip_runtime.h>

#define F 128
#define RPB 64          // rows per bucket
#define MAXNB 1792      // LDS bucket-histogram capacity
#define CHUNK 8192      // edges per rank-scatter block
#define EPT 32          // edges per thread (CHUNK/256)
#define SCAN_CHUNK 1024
#define SCAN_T 256

// ---------------- fallback: atomic COO (round-4 proven) ----------------
__global__ void spmm_coo_atomic(const int* __restrict__ rows,
                                const int* __restrict__ cols,
                                const float* __restrict__ vals,
                                const float* __restrict__ x,
                                float* __restrict__ out,
                                int nnz, int n_rows) {
    int t = blockIdx.x * blockDim.x + threadIdx.x;
    int e = t >> 5;
    int g = t & 31;
    if (e >= nnz) return;
    int r = rows[e];
    int c = cols[e];
    float v = vals[e];
    if ((unsigned)r >= (unsigned)n_rows || (unsigned)c >= (unsigned)n_rows) return;
    const float4 xv = *reinterpret_cast<const float4*>(x + (size_t)c * F + g * 4);
    float* o = out + (size_t)r * F + g * 4;
    atomicAdd(o + 0, v * xv.x);
    atomicAdd(o + 1, v * xv.y);
    atomicAdd(o + 2, v * xv.z);
    atomicAdd(o + 3, v * xv.w);
}

// ---------------- exact per-row histogram ----------------
__global__ void k_histo(const int* __restrict__ rows, int* __restrict__ counts,
                        int nnz, int n) {
    int e = blockIdx.x * blockDim.x + threadIdx.x;
    if (e < nnz) {
        int r = rows[e];
        if ((unsigned)r < (unsigned)n) atomicAdd(&counts[r], 1);
    }
}

// ---------------- exclusive scan over n counters (3-phase) ----------------
__global__ void k_scan1(const int* __restrict__ counts, int* __restrict__ offs,
                        int* __restrict__ blocksums, int n) {
    __shared__ int s[SCAN_T];
    int tid = threadIdx.x;
    int base = blockIdx.x * SCAN_CHUNK + tid * 4;
    int v[4];
#pragma unroll
    for (int k = 0; k < 4; ++k) {
        int i = base + k;
        v[k] = (i < n) ? counts[i] : 0;
    }
    int tsum = v[0] + v[1] + v[2] + v[3];
    s[tid] = tsum;
    __syncthreads();
    for (int off = 1; off < SCAN_T; off <<= 1) {
        int t = (tid >= off) ? s[tid - off] : 0;
        __syncthreads();
        s[tid] += t;
        __syncthreads();
    }
    int run = s[tid] - tsum;
#pragma unroll
    for (int k = 0; k < 4; ++k) {
        int i = base + k;
        if (i < n) offs[i] = run;
        run += v[k];
    }
    if (tid == SCAN_T - 1) blocksums[blockIdx.x] = s[SCAN_T - 1];
}

__global__ void k_scan2(int* __restrict__ blocksums, int nb) {
    __shared__ int s[SCAN_T];
    int tid = threadIdx.x;
    int v = (tid < nb) ? blocksums[tid] : 0;
    s[tid] = v;
    __syncthreads();
    for (int off = 1; off < SCAN_T; off <<= 1) {
        int t = (tid >= off) ? s[tid - off] : 0;
        __syncthreads();
        s[tid] += t;
        __syncthreads();
    }
    if (tid < nb) blocksums[tid] = s[tid] - v;
}

__global__ void k_scan3(int* __restrict__ offs, const int* __restrict__ blocksums,
                        int n, int nnz_total) {
    int base = blockIdx.x * SCAN_CHUNK + threadIdx.x * 4;
    int add = blocksums[blockIdx.x];
#pragma unroll
    for (int k = 0; k < 4; ++k) {
        int idx = base + k;
        if (idx < n) offs[idx] += add;
    }
    if (blockIdx.x == 0 && threadIdx.x == 0) offs[n] = nnz_total;
}

// gcur[b] = offs[b*RPB]  (bucket start cursor)
__global__ void k_seed_gcur(const int* __restrict__ offs, int* __restrict__ gcur, int nbk) {
    int b = blockIdx.x * blockDim.x + threadIdx.x;
    if (b < nbk) gcur[b] = offs[b * RPB];
}

// ---------------- bucket-level ranked scatter (coalesced runs) ----------------
__global__ void k_rank_scatter(const int* __restrict__ rows, const int* __restrict__ cols,
                               const float* __restrict__ vals, int* __restrict__ gcur,
                               int2* __restrict__ pair, int nnz, int nbk, int n) {
    __shared__ int lcnt[MAXNB];
    __shared__ int lbase[MAXNB];
    for (int i = threadIdx.x; i < nbk; i += 256) lcnt[i] = 0;
    __syncthreads();
    int base = blockIdx.x * CHUNK;
    unsigned br[EPT];                 // packed (bucket << 13) | rank, rank < 8192
#pragma unroll
    for (int k = 0; k < EPT; ++k) {
        int e = base + k * 256 + threadIdx.x;
        br[k] = 0xFFFFFFFFu;
        if (e < nnz) {
            int r = rows[e];
            if ((unsigned)r < (unsigned)n) {
                int b = r / RPB;
                int rk = atomicAdd(&lcnt[b], 1);
                br[k] = ((unsigned)b << 13) | (unsigned)rk;
            }
        }
    }
    __syncthreads();
    for (int i = threadIdx.x; i < nbk; i += 256) {
        int c = lcnt[i];
        if (c) lbase[i] = atomicAdd(&gcur[i], c);
    }
    __syncthreads();
#pragma unroll
    for (int k = 0; k < EPT; ++k) {
        if (br[k] != 0xFFFFFFFFu) {
            int e = base + k * 256 + threadIdx.x;
            int b = br[k] >> 13;
            int rk = br[k] & 0x1FFF;
            int lr = rows[e] - b * RPB;           // localrow in [0, RPB)
            int c = cols[e];
            if ((unsigned)c >= (unsigned)n) c = 0;
            int pos = lbase[b] + rk;
            pair[pos] = make_int2((lr << 17) | c, __float_as_int(vals[e]));
        }
    }
}

// ---------------- within-bucket counting sort -> exact CSR ----------------
// Block b exclusively owns rows [b*RPB, b*RPB+RPB): LDS cursors, scatter into
// pair2 at exact CSR positions (writes stay inside the bucket's own window).
__global__ void k_bucket_sort(const int* __restrict__ offs, const int2* __restrict__ pair,
                              int2* __restrict__ pair2, int n, int nnz) {
    __shared__ int cur[RPB];
    int b = blockIdx.x;
    int tid = threadIdx.x;
    if (tid < RPB) {
        int idx = b * RPB + tid;
        cur[tid] = (idx <= n) ? offs[idx] : nnz;   // offs has n+1 entries
    }
    __syncthreads();
    int beg = offs[b * RPB];
    int row_end = b * RPB + RPB;
    int end = (row_end <= n) ? offs[row_end] : nnz;
    for (int j = beg + tid; j < end; j += 256) {
        int2 pr = pair[j];
        int lr = pr.x >> 17;
        int pos = atomicAdd(&cur[lr], 1);
        pair2[pos] = make_int2(pr.x & 0x1FFFF, pr.y);   // store pure col
    }
}

// ---------------- CSR SpMM: one wave per row, 2 edges per inner iteration ----
__global__ void k_spmm_csr(const int* __restrict__ offs, const int2* __restrict__ pair_s,
                           const float* __restrict__ x, float* __restrict__ out,
                           int n_rows) {
    int gid = blockIdx.x * blockDim.x + threadIdx.x;
    int row = gid >> 6;          // one 64-lane wave per row
    int lane = threadIdx.x & 63;
    if (row >= n_rows) return;
    int half = lane >> 5;        // which of the 2 concurrent edges this lane serves
    int fl = lane & 31;          // feature-lane: owns 4 floats
    int beg = offs[row], end = offs[row + 1];

    float4 acc = make_float4(0.f, 0.f, 0.f, 0.f);
    for (int i = beg; i < end; i += 64) {
        int j = i + lane;
        int c = 0;
        float v = 0.f;
        if (j < end) {
            int2 pr = pair_s[j];
            c = pr.x;
            v = __int_as_float(pr.y);
        }
        int m = min(64, end - i);   // wave-uniform
        for (int k = 0; k < m; k += 2) {
            int kk = k + half;                 // lanes<32: edge k, lanes>=32: edge k+1
            int ck = __shfl(c, kk);            // out-of-range kk reads (0, 0.f) — safe
            float vk = __shfl(v, kk);
            const float4 xv = *reinterpret_cast<const float4*>(x + (size_t)ck * F + fl * 4);
            acc.x += vk * xv.x;
            acc.y += vk * xv.y;
            acc.z += vk * xv.z;
            acc.w += vk * xv.w;
        }
    }
    acc.x += __shfl_xor(acc.x, 32);
    acc.y += __shfl_xor(acc.y, 32);
    acc.z += __shfl_xor(acc.z, 32);
    acc.w += __shfl_xor(acc.w, 32);
    if (half == 0) {
        *reinterpret_cast<float4*>(out + (size_t)row * F + fl * 4) = acc;
    }
}

extern "C" void kernel_launch(void* const* d_in, const int* in_sizes, int n_in,
                              void* d_out, int out_size, void* d_ws, size_t ws_size,
                              hipStream_t stream) {
    const float* x = (const float*)d_in[0];
    const int* A_ind = (const int*)d_in[1];
    const float* A_val = (const float*)d_in[2];
    float* out = (float*)d_out;

    const int nnz = in_sizes[2];
    const int n = out_size / F;              // 100000
    const int nbk = (n + RPB - 1) / RPB;     // 1563 buckets
    const int* rows = A_ind;
    const int* cols = A_ind + nnz;

    const int nsb = (n + SCAN_CHUNK - 1) / SCAN_CHUNK;   // scan blocks (98)

    const size_t need = (size_t)nnz * 16                 // pair + pair2
                      + (size_t)n * 4                    // counts
                      + (size_t)(n + 1) * 4              // offs
                      + 256 * 4                          // blocksums
                      + (size_t)nbk * 4 + 64;            // gcur

    if (nbk > MAXNB || nsb > SCAN_T || ws_size < need) {
        hipMemsetAsync(d_out, 0, (size_t)out_size * sizeof(float), stream);
        const long long total = (long long)nnz * 32;
        spmm_coo_atomic<<<(int)((total + 255) / 256), 256, 0, stream>>>(
            rows, cols, A_val, x, out, nnz, n);
        return;
    }

    char* w = (char*)d_ws;
    int2* pair = (int2*)w;     w += (size_t)nnz * 8;
    int2* pair2 = (int2*)w;    w += (size_t)nnz * 8;
    int* counts = (int*)w;     w += (size_t)n * 4;
    int* offs = (int*)w;       w += (size_t)(n + 1) * 4;
    int* blocksums = (int*)w;  w += 256 * 4;
    int* gcur = (int*)w;

    const int nchunks = (nnz + CHUNK - 1) / CHUNK;

    hipMemsetAsync(counts, 0, (size_t)n * 4, stream);
    k_histo<<<(nnz + 255) / 256, 256, 0, stream>>>(rows, counts, nnz, n);
    k_scan1<<<nsb, SCAN_T, 0, stream>>>(counts, offs, blocksums, n);
    k_scan2<<<1, SCAN_T, 0, stream>>>(blocksums, nsb);
    k_scan3<<<nsb, SCAN_T, 0, stream>>>(offs, blocksums, n, nnz);
    k_seed_gcur<<<(nbk + 255) / 256, 256, 0, stream>>>(offs, gcur, nbk);
    k_rank_scatter<<<nchunks, 256, 0, stream>>>(rows, cols, A_val, gcur, pair,
                                                nnz, nbk, n);
    k_bucket_sort<<<nbk, 256, 0, stream>>>(offs, pair, pair2, n, nnz);
    // Writes every output row exactly once (zeros for empty rows) -> no out memset.
    k_spmm_csr<<<(n * 64 + 255) / 256, 256, 0, stream>>>(offs, pair2, x, out, n);
}

// Round 10
// 326.988 us; speedup vs baseline: 7.5248x; 1.3635x over previous
//
#include <hip/hip_runtime.h>

#define F 128
#define RPB 64          // rows per bucket
#define MAXNB 1792      // LDS bucket-histogram capacity
#define CHUNK 8192      // edges per rank-scatter block
#define EPT 32          // edges per thread (CHUNK/256)
#define CAP 3072        // LDS edge capacity per sort/spmm batch (> max bucket size)
#define HELD (CAP/256)  // 12 edges held in registers per thread

// ---------------- fallback: atomic COO (round-4 proven) ----------------
__global__ void spmm_coo_atomic(const int* __restrict__ rows,
                                const int* __restrict__ cols,
                                const float* __restrict__ vals,
                                const float* __restrict__ x,
                                float* __restrict__ out,
                                int nnz, int n_rows) {
    int t = blockIdx.x * blockDim.x + threadIdx.x;
    int e = t >> 5;
    int g = t & 31;
    if (e >= nnz) return;
    int r = rows[e];
    int c = cols[e];
    float v = vals[e];
    if ((unsigned)r >= (unsigned)n_rows || (unsigned)c >= (unsigned)n_rows) return;
    const float4 xv = *reinterpret_cast<const float4*>(x + (size_t)c * F + g * 4);
    float* o = out + (size_t)r * F + g * 4;
    atomicAdd(o + 0, v * xv.x);
    atomicAdd(o + 1, v * xv.y);
    atomicAdd(o + 2, v * xv.z);
    atomicAdd(o + 3, v * xv.w);
}

// ---------------- K0: x fp32 -> bf16 (RNE) ----------------
__device__ __forceinline__ unsigned f2bf(float f) {
    unsigned u = __float_as_uint(f);
    return (u + 0x7FFFu + ((u >> 16) & 1u)) >> 16;   // round-to-nearest-even
}

__global__ void k_cvt_bf16(const float* __restrict__ x, unsigned short* __restrict__ xb,
                           long long total) {
    long long i = ((long long)blockIdx.x * 256 + threadIdx.x) * 8;
    if (i >= total) return;
    float4 a = *reinterpret_cast<const float4*>(x + i);
    float4 b = *reinterpret_cast<const float4*>(x + i + 4);
    uint4 o;
    o.x = f2bf(a.x) | (f2bf(a.y) << 16);
    o.y = f2bf(a.z) | (f2bf(a.w) << 16);
    o.z = f2bf(b.x) | (f2bf(b.y) << 16);
    o.w = f2bf(b.z) | (f2bf(b.w) << 16);
    *reinterpret_cast<uint4*>(xb + i) = o;
}

// ---------------- K1: block-aggregated bucket histogram ----------------
__global__ void k_bucket_histo(const int* __restrict__ rows, int* __restrict__ cnt,
                               int nnz, int nbk, int n) {
    __shared__ int lc[MAXNB];
    for (int i = threadIdx.x; i < nbk; i += 256) lc[i] = 0;
    __syncthreads();
    int base = blockIdx.x * CHUNK;
#pragma unroll
    for (int k = 0; k < EPT; ++k) {
        int e = base + k * 256 + threadIdx.x;
        if (e < nnz) {
            int r = rows[e];
            if ((unsigned)r < (unsigned)n) atomicAdd(&lc[r / RPB], 1);
        }
    }
    __syncthreads();
    for (int i = threadIdx.x; i < nbk; i += 256) {
        int c = lc[i];
        if (c) atomicAdd(&cnt[i], c);
    }
}

// ---------------- K2: single-block exclusive scan over buckets ----------------
__global__ void k_bucket_scan(const int* __restrict__ cnt, int* __restrict__ off,
                              int* __restrict__ gcur, int nbk) {
    __shared__ int s[256];
    int tid = threadIdx.x;
    int per = (nbk + 255) / 256;      // <= 7 for nbk <= 1792
    int base = tid * per;
    int loc[8];
    int tsum = 0;
#pragma unroll
    for (int k = 0; k < 8; ++k) {
        int i = base + k;
        int v = (k < per && i < nbk) ? cnt[i] : 0;
        loc[k] = v;
        tsum += v;
    }
    s[tid] = tsum;
    __syncthreads();
    for (int o = 1; o < 256; o <<= 1) {
        int t = (tid >= o) ? s[tid - o] : 0;
        __syncthreads();
        s[tid] += t;
        __syncthreads();
    }
    int run = s[tid] - tsum;
#pragma unroll
    for (int k = 0; k < 8; ++k) {
        int i = base + k;
        if (k < per && i < nbk) { off[i] = run; gcur[i] = run; }
        run += loc[k];
    }
    if (tid == 255) off[nbk] = s[255];
}

// ---------------- K3: ranked bucket scatter (coalesced runs) ----------------
__global__ void k_rank_scatter(const int* __restrict__ rows, const int* __restrict__ cols,
                               const float* __restrict__ vals, int* __restrict__ gcur,
                               int2* __restrict__ pair, int nnz, int nbk, int n) {
    __shared__ int lcnt[MAXNB];
    __shared__ int lbase[MAXNB];
    for (int i = threadIdx.x; i < nbk; i += 256) lcnt[i] = 0;
    __syncthreads();
    int base = blockIdx.x * CHUNK;
    unsigned br[EPT];                 // packed (bucket << 13) | rank, rank < 8192
#pragma unroll
    for (int k = 0; k < EPT; ++k) {
        int e = base + k * 256 + threadIdx.x;
        br[k] = 0xFFFFFFFFu;
        if (e < nnz) {
            int r = rows[e];
            if ((unsigned)r < (unsigned)n) {
                int b = r / RPB;
                int rk = atomicAdd(&lcnt[b], 1);
                br[k] = ((unsigned)b << 13) | (unsigned)rk;
            }
        }
    }
    __syncthreads();
    for (int i = threadIdx.x; i < nbk; i += 256) {
        int c = lcnt[i];
        if (c) lbase[i] = atomicAdd(&gcur[i], c);
    }
    __syncthreads();
#pragma unroll
    for (int k = 0; k < EPT; ++k) {
        if (br[k] != 0xFFFFFFFFu) {
            int e = base + k * 256 + threadIdx.x;
            int b = br[k] >> 13;
            int rk = br[k] & 0x1FFF;
            int lr = rows[e] - b * RPB;           // localrow in [0, RPB)
            int c = cols[e];
            if ((unsigned)c >= (unsigned)n) c = 0;
            int pos = lbase[b] + rk;
            pair[pos] = make_int2((lr << 17) | c, __float_as_int(vals[e]));
        }
    }
}

// ---------------- K4: fused within-bucket sort + SpMM ----------------
// One block per bucket. Batch-loads the bucket's coalesced pair run, counting-
// sorts it into LDS (64 cursors), then 4 waves each own 16 rows: half-split
// dual-edge bf16 gathers, fp32 register accumulation, single coalesced write.
__global__ void __launch_bounds__(256) k_sort_spmm(const int* __restrict__ off,
                                                   const int2* __restrict__ pair,
                                                   const unsigned short* __restrict__ xb,
                                                   float* __restrict__ out, int n) {
    __shared__ int2 eb[CAP];
    __shared__ int rcnt[RPB];
    __shared__ int rst[RPB + 1];
    __shared__ int rcur[RPB];

    int b = blockIdx.x;
    int tid = threadIdx.x;
    int wave = tid >> 6;
    int lane = tid & 63;
    int half = lane >> 5;
    int fl = lane & 31;

    int beg = off[b], end = off[b + 1];
    bool first = true;
    int bb = beg;
    do {
        int bn = min(CAP, end - bb);   // may be 0 for an empty bucket
        if (tid < RPB) rcnt[tid] = 0;
        __syncthreads();

        // load batch edges into registers, count per localrow
        int2 held[HELD];
#pragma unroll
        for (int k = 0; k < HELD; ++k) {
            int j = tid + k * 256;
            held[k] = make_int2(0, 0);
            if (j < bn) {
                int2 pr = pair[bb + j];
                held[k] = pr;
                atomicAdd(&rcnt[pr.x >> 17], 1);
            }
        }
        __syncthreads();

        // wave-0 inclusive scan of the 64 row counts
        if (tid < 64) {
            int v = rcnt[tid];
            int s = v;
            for (int o = 1; o < 64; o <<= 1) {
                int t = __shfl_up(s, o);
                if (tid >= o) s += t;
            }
            rst[tid + 1] = s;
            if (tid == 0) rst[0] = 0;
            rcur[tid] = s - v;
        }
        __syncthreads();

        // scatter held edges into row-sorted LDS positions
#pragma unroll
        for (int k = 0; k < HELD; ++k) {
            int j = tid + k * 256;
            if (j < bn) {
                int2 pr = held[k];
                int lr = pr.x >> 17;
                int pos = atomicAdd(&rcur[lr], 1);
                eb[pos] = make_int2(pr.x & 0x1FFFF, pr.y);
            }
        }
        __syncthreads();

        // SpMM: wave owns rows [wave*16, wave*16+16)
        for (int rr = 0; rr < 16; ++rr) {
            int lr = wave * 16 + rr;
            int s0 = rst[lr], s1 = rst[lr + 1];
            float4 acc = make_float4(0.f, 0.f, 0.f, 0.f);
            for (int j = s0; j < s1; j += 2) {
                int jj = j + half;
                float vk = 0.f;
                int col = 0;
                if (jj < s1) {
                    int2 e = eb[jj];
                    col = e.x;
                    vk = __int_as_float(e.y);
                }
                uint2 w = *reinterpret_cast<const uint2*>(xb + (size_t)col * F + fl * 4);
                acc.x += vk * __uint_as_float(w.x << 16);
                acc.y += vk * __uint_as_float(w.x & 0xFFFF0000u);
                acc.z += vk * __uint_as_float(w.y << 16);
                acc.w += vk * __uint_as_float(w.y & 0xFFFF0000u);
            }
            acc.x += __shfl_xor(acc.x, 32);
            acc.y += __shfl_xor(acc.y, 32);
            acc.z += __shfl_xor(acc.z, 32);
            acc.w += __shfl_xor(acc.w, 32);
            if (half == 0) {
                long long row = (long long)b * RPB + lr;
                if (row < n) {
                    float* po = out + (size_t)row * F + fl * 4;
                    if (first) {
                        *reinterpret_cast<float4*>(po) = acc;
                    } else {
                        float4 t = *reinterpret_cast<const float4*>(po);
                        t.x += acc.x; t.y += acc.y; t.z += acc.z; t.w += acc.w;
                        *reinterpret_cast<float4*>(po) = t;
                    }
                }
            }
        }
        first = false;
        bb += CAP;
        __syncthreads();   // protect eb before next batch
    } while (bb < end);
}

extern "C" void kernel_launch(void* const* d_in, const int* in_sizes, int n_in,
                              void* d_out, int out_size, void* d_ws, size_t ws_size,
                              hipStream_t stream) {
    const float* x = (const float*)d_in[0];
    const int* A_ind = (const int*)d_in[1];
    const float* A_val = (const float*)d_in[2];
    float* out = (float*)d_out;

    const int nnz = in_sizes[2];
    const int n = out_size / F;              // 100000
    const int nbk = (n + RPB - 1) / RPB;     // 1563 buckets
    const int* rows = A_ind;
    const int* cols = A_ind + nnz;

    const long long xtotal = (long long)n * F;

    const size_t need = (size_t)nnz * 8              // pair
                      + (size_t)xtotal * 2           // x bf16
                      + (size_t)(3 * nbk + 1) * 4 + 128;

    if (nbk > MAXNB || (xtotal % 8) != 0 || ws_size < need) {
        hipMemsetAsync(d_out, 0, (size_t)out_size * sizeof(float), stream);
        const long long total = (long long)nnz * 32;
        spmm_coo_atomic<<<(int)((total + 255) / 256), 256, 0, stream>>>(
            rows, cols, A_val, x, out, nnz, n);
        return;
    }

    char* w = (char*)d_ws;
    int2* pair = (int2*)w;            w += (size_t)nnz * 8;
    unsigned short* xb = (unsigned short*)w;  w += (size_t)xtotal * 2;
    int* cnt = (int*)w;               w += (size_t)nbk * 4;
    int* off = (int*)w;               w += (size_t)(nbk + 1) * 4;
    int* gcur = (int*)w;

    const int nchunks = (nnz + CHUNK - 1) / CHUNK;

    k_cvt_bf16<<<(int)(xtotal / 8 + 255) / 256, 256, 0, stream>>>(x, xb, xtotal);
    hipMemsetAsync(cnt, 0, (size_t)nbk * 4, stream);
    k_bucket_histo<<<nchunks, 256, 0, stream>>>(rows, cnt, nnz, nbk, n);
    k_bucket_scan<<<1, 256, 0, stream>>>(cnt, off, gcur, nbk);
    k_rank_scatter<<<nchunks, 256, 0, stream>>>(rows, cols, A_val, gcur, pair,
                                                nnz, nbk, n);
    // Writes every output row exactly once (zeros for empty rows) -> no out memset.
    k_sort_spmm<<<nbk, 256, 0, stream>>>(off, pair, xb, out, n);
}

// Round 11
// 223.496 us; speedup vs baseline: 11.0092x; 1.4631x over previous
//
#include <hip/hip_runtime.h>

#define F 128
#define RPB 64          // rows per bucket
#define MAXNB 1792      // LDS bucket-histogram capacity
#define CHUNK 8192      // edges per rank-scatter block
#define EPT 32          // edges per thread (CHUNK/256)
#define CAP 3072        // LDS edge capacity per sort/spmm batch (> max bucket size)
#define SPMM_T 512      // threads in fused sort+spmm block (8 waves)
#define HELD (CAP/SPMM_T)

// ---------------- fallback: atomic COO (round-4 proven) ----------------
__global__ void spmm_coo_atomic(const int* __restrict__ rows,
                                const int* __restrict__ cols,
                                const float* __restrict__ vals,
                                const float* __restrict__ x,
                                float* __restrict__ out,
                                int nnz, int n_rows) {
    int t = blockIdx.x * blockDim.x + threadIdx.x;
    int e = t >> 5;
    int g = t & 31;
    if (e >= nnz) return;
    int r = rows[e];
    int c = cols[e];
    float v = vals[e];
    if ((unsigned)r >= (unsigned)n_rows || (unsigned)c >= (unsigned)n_rows) return;
    const float4 xv = *reinterpret_cast<const float4*>(x + (size_t)c * F + g * 4);
    float* o = out + (size_t)r * F + g * 4;
    atomicAdd(o + 0, v * xv.x);
    atomicAdd(o + 1, v * xv.y);
    atomicAdd(o + 2, v * xv.z);
    atomicAdd(o + 3, v * xv.w);
}

// ---------------- K0: x fp32 -> bf16 (RNE) ----------------
__device__ __forceinline__ unsigned f2bf(float f) {
    unsigned u = __float_as_uint(f);
    return (u + 0x7FFFu + ((u >> 16) & 1u)) >> 16;   // round-to-nearest-even
}

__global__ void k_cvt_bf16(const float* __restrict__ x, unsigned short* __restrict__ xb,
                           long long total) {
    long long i = ((long long)blockIdx.x * 256 + threadIdx.x) * 8;
    if (i >= total) return;
    float4 a = *reinterpret_cast<const float4*>(x + i);
    float4 b = *reinterpret_cast<const float4*>(x + i + 4);
    uint4 o;
    o.x = f2bf(a.x) | (f2bf(a.y) << 16);
    o.y = f2bf(a.z) | (f2bf(a.w) << 16);
    o.z = f2bf(b.x) | (f2bf(b.y) << 16);
    o.w = f2bf(b.z) | (f2bf(b.w) << 16);
    *reinterpret_cast<uint4*>(xb + i) = o;
}

// ---------------- K1: block-aggregated bucket histogram ----------------
__global__ void k_bucket_histo(const int* __restrict__ rows, int* __restrict__ cnt,
                               int nnz, int nbk, int n) {
    __shared__ int lc[MAXNB];
    for (int i = threadIdx.x; i < nbk; i += 256) lc[i] = 0;
    __syncthreads();
    int base = blockIdx.x * CHUNK;
#pragma unroll
    for (int k = 0; k < EPT; ++k) {
        int e = base + k * 256 + threadIdx.x;
        if (e < nnz) {
            int r = rows[e];
            if ((unsigned)r < (unsigned)n) atomicAdd(&lc[r / RPB], 1);
        }
    }
    __syncthreads();
    for (int i = threadIdx.x; i < nbk; i += 256) {
        int c = lc[i];
        if (c) atomicAdd(&cnt[i], c);
    }
}

// ---------------- K2: single-block exclusive scan over buckets ----------------
__global__ void k_bucket_scan(const int* __restrict__ cnt, int* __restrict__ off,
                              int* __restrict__ gcur, int nbk) {
    __shared__ int s[256];
    int tid = threadIdx.x;
    int per = (nbk + 255) / 256;      // <= 7 for nbk <= 1792
    int base = tid * per;
    int loc[8];
    int tsum = 0;
#pragma unroll
    for (int k = 0; k < 8; ++k) {
        int i = base + k;
        int v = (k < per && i < nbk) ? cnt[i] : 0;
        loc[k] = v;
        tsum += v;
    }
    s[tid] = tsum;
    __syncthreads();
    for (int o = 1; o < 256; o <<= 1) {
        int t = (tid >= o) ? s[tid - o] : 0;
        __syncthreads();
        s[tid] += t;
        __syncthreads();
    }
    int run = s[tid] - tsum;
#pragma unroll
    for (int k = 0; k < 8; ++k) {
        int i = base + k;
        if (k < per && i < nbk) { off[i] = run; gcur[i] = run; }
        run += loc[k];
    }
    if (tid == 255) off[nbk] = s[255];
}

// ---------------- K3: ranked bucket scatter (coalesced runs) ----------------
__global__ void k_rank_scatter(const int* __restrict__ rows, const int* __restrict__ cols,
                               const float* __restrict__ vals, int* __restrict__ gcur,
                               int2* __restrict__ pair, int nnz, int nbk, int n) {
    __shared__ int lcnt[MAXNB];
    __shared__ int lbase[MAXNB];
    for (int i = threadIdx.x; i < nbk; i += 256) lcnt[i] = 0;
    __syncthreads();
    int base = blockIdx.x * CHUNK;
    unsigned br[EPT];                 // packed (bucket << 13) | rank, rank < 8192
#pragma unroll
    for (int k = 0; k < EPT; ++k) {
        int e = base + k * 256 + threadIdx.x;
        br[k] = 0xFFFFFFFFu;
        if (e < nnz) {
            int r = rows[e];
            if ((unsigned)r < (unsigned)n) {
                int b = r / RPB;
                int rk = atomicAdd(&lcnt[b], 1);
                br[k] = ((unsigned)b << 13) | (unsigned)rk;
            }
        }
    }
    __syncthreads();
    for (int i = threadIdx.x; i < nbk; i += 256) {
        int c = lcnt[i];
        if (c) lbase[i] = atomicAdd(&gcur[i], c);
    }
    __syncthreads();
#pragma unroll
    for (int k = 0; k < EPT; ++k) {
        if (br[k] != 0xFFFFFFFFu) {
            int e = base + k * 256 + threadIdx.x;
            int b = br[k] >> 13;
            int rk = br[k] & 0x1FFF;
            int lr = rows[e] - b * RPB;           // localrow in [0, RPB)
            int c = cols[e];
            if ((unsigned)c >= (unsigned)n) c = 0;
            int pos = lbase[b] + rk;
            pair[pos] = make_int2((lr << 17) | c, __float_as_int(vals[e]));
        }
    }
}

// ---------------- K4: fused within-bucket sort + SpMM (8 waves) ----------------
// One block per bucket. Counting-sorts the bucket's coalesced pair run into LDS,
// then 8 waves each own 8 rows; 16-lane quarter-waves process 4 edges/iter with
// uint4 (8 bf16) gathers; fp32 register accumulation; one coalesced write.
__global__ void __launch_bounds__(SPMM_T) k_sort_spmm(const int* __restrict__ off,
                                                      const int2* __restrict__ pair,
                                                      const unsigned short* __restrict__ xb,
                                                      float* __restrict__ out, int n) {
    __shared__ int2 eb[CAP];
    __shared__ int rcnt[RPB];
    __shared__ int rst[RPB + 1];
    __shared__ int rcur[RPB];

    int b = blockIdx.x;
    int tid = threadIdx.x;
    int wave = tid >> 6;        // 0..7
    int lane = tid & 63;
    int q = lane >> 4;          // quarter 0..3 (edge slot)
    int fl = lane & 15;         // feature lane: owns 8 bf16 (16B)

    int beg = off[b], end = off[b + 1];
    bool first = true;
    int bb = beg;
    do {
        int bn = min(CAP, end - bb);   // may be 0 for an empty bucket
        if (tid < RPB) rcnt[tid] = 0;
        __syncthreads();

        // load batch edges into registers, count per localrow
        int2 held[HELD];
#pragma unroll
        for (int k = 0; k < HELD; ++k) {
            int j = tid + k * SPMM_T;
            held[k] = make_int2(0, 0);
            if (j < bn) {
                int2 pr = pair[bb + j];
                held[k] = pr;
                atomicAdd(&rcnt[pr.x >> 17], 1);
            }
        }
        __syncthreads();

        // wave-0 inclusive scan of the 64 row counts
        if (tid < 64) {
            int v = rcnt[tid];
            int s = v;
            for (int o = 1; o < 64; o <<= 1) {
                int t = __shfl_up(s, o);
                if (tid >= o) s += t;
            }
            rst[tid + 1] = s;
            if (tid == 0) rst[0] = 0;
            rcur[tid] = s - v;
        }
        __syncthreads();

        // scatter held edges into row-sorted LDS positions
#pragma unroll
        for (int k = 0; k < HELD; ++k) {
            int j = tid + k * SPMM_T;
            if (j < bn) {
                int2 pr = held[k];
                int lr = pr.x >> 17;
                int pos = atomicAdd(&rcur[lr], 1);
                eb[pos] = make_int2(pr.x & 0x1FFFF, pr.y);
            }
        }
        __syncthreads();

        // SpMM: wave owns rows [wave*8, wave*8+8)
        for (int rr = 0; rr < 8; ++rr) {
            int lr = wave * 8 + rr;
            int s0 = rst[lr], s1 = rst[lr + 1];
            float acc[8] = {0.f, 0.f, 0.f, 0.f, 0.f, 0.f, 0.f, 0.f};
#pragma unroll 2
            for (int j = s0 + q; j < s1; j += 4) {
                int2 e = eb[j];            // broadcast within the 16-lane quarter
                int col = e.x;
                float vk = __int_as_float(e.y);
                uint4 w = *reinterpret_cast<const uint4*>(xb + (size_t)col * F + fl * 8);
                acc[0] += vk * __uint_as_float(w.x << 16);
                acc[1] += vk * __uint_as_float(w.x & 0xFFFF0000u);
                acc[2] += vk * __uint_as_float(w.y << 16);
                acc[3] += vk * __uint_as_float(w.y & 0xFFFF0000u);
                acc[4] += vk * __uint_as_float(w.z << 16);
                acc[5] += vk * __uint_as_float(w.z & 0xFFFF0000u);
                acc[6] += vk * __uint_as_float(w.w << 16);
                acc[7] += vk * __uint_as_float(w.w & 0xFFFF0000u);
            }
            // combine the 4 quarters: lanes fl, fl+16, fl+32, fl+48
#pragma unroll
            for (int i = 0; i < 8; ++i) {
                acc[i] += __shfl_xor(acc[i], 16);
                acc[i] += __shfl_xor(acc[i], 32);
            }
            if (q == 0) {
                long long row = (long long)b * RPB + lr;
                if (row < n) {
                    float* po = out + (size_t)row * F + fl * 8;
                    float4 lo = make_float4(acc[0], acc[1], acc[2], acc[3]);
                    float4 hi = make_float4(acc[4], acc[5], acc[6], acc[7]);
                    if (first) {
                        *reinterpret_cast<float4*>(po) = lo;
                        *reinterpret_cast<float4*>(po + 4) = hi;
                    } else {
                        float4 t0 = *reinterpret_cast<const float4*>(po);
                        float4 t1 = *reinterpret_cast<const float4*>(po + 4);
                        t0.x += lo.x; t0.y += lo.y; t0.z += lo.z; t0.w += lo.w;
                        t1.x += hi.x; t1.y += hi.y; t1.z += hi.z; t1.w += hi.w;
                        *reinterpret_cast<float4*>(po) = t0;
                        *reinterpret_cast<float4*>(po + 4) = t1;
                    }
                }
            }
        }
        first = false;
        bb += CAP;
        __syncthreads();   // protect eb before next batch
    } while (bb < end);
}

extern "C" void kernel_launch(void* const* d_in, const int* in_sizes, int n_in,
                              void* d_out, int out_size, void* d_ws, size_t ws_size,
                              hipStream_t stream) {
    const float* x = (const float*)d_in[0];
    const int* A_ind = (const int*)d_in[1];
    const float* A_val = (const float*)d_in[2];
    float* out = (float*)d_out;

    const int nnz = in_sizes[2];
    const int n = out_size / F;              // 100000
    const int nbk = (n + RPB - 1) / RPB;     // 1563 buckets
    const int* rows = A_ind;
    const int* cols = A_ind + nnz;

    const long long xtotal = (long long)n * F;

    const size_t need = (size_t)nnz * 8              // pair
                      + (size_t)xtotal * 2           // x bf16
                      + (size_t)(3 * nbk + 1) * 4 + 128;

    if (nbk > MAXNB || (xtotal % 8) != 0 || ws_size < need) {
        hipMemsetAsync(d_out, 0, (size_t)out_size * sizeof(float), stream);
        const long long total = (long long)nnz * 32;
        spmm_coo_atomic<<<(int)((total + 255) / 256), 256, 0, stream>>>(
            rows, cols, A_val, x, out, nnz, n);
        return;
    }

    char* w = (char*)d_ws;
    int2* pair = (int2*)w;            w += (size_t)nnz * 8;
    unsigned short* xb = (unsigned short*)w;  w += (size_t)xtotal * 2;
    int* cnt = (int*)w;               w += (size_t)nbk * 4;
    int* off = (int*)w;               w += (size_t)(nbk + 1) * 4;
    int* gcur = (int*)w;

    const int nchunks = (nnz + CHUNK - 1) / CHUNK;

    k_cvt_bf16<<<(int)(xtotal / 8 + 255) / 256, 256, 0, stream>>>(x, xb, xtotal);
    hipMemsetAsync(cnt, 0, (size_t)nbk * 4, stream);
    k_bucket_histo<<<nchunks, 256, 0, stream>>>(rows, cnt, nnz, nbk, n);
    k_bucket_scan<<<1, 256, 0, stream>>>(cnt, off, gcur, nbk);
    k_rank_scatter<<<nchunks, 256, 0, stream>>>(rows, cols, A_val, gcur, pair,
                                                nnz, nbk, n);
    // Writes every output row exactly once (zeros for empty rows) -> no out memset.
    k_sort_spmm<<<nbk, SPMM_T, 0, stream>>>(off, pair, xb, out, n);
}